// Round 5
// baseline (528.981 us; speedup 1.0000x reference)
//
#include <hip/hip_runtime.h>

#define NB    4
#define NPTS  4096
#define DF    32      // D*C
#define DD    4
#define CC    8
#define CO    16
#define KNN   16
#define HALF  (NPTS/2) // candidates per wave (2-way split across wave pair)
#define FIFO_N 128     // per-row pending ring (max pending 63+64=127)

__device__ __forceinline__ unsigned sortable32(float f) {
    unsigned u = __float_as_uint(f);
    return (u & 0x80000000u) ? ~u : (u | 0x80000000u);
}

// Full-wave ascending bitonic sort of one u32 per lane (verified R3/R4).
__device__ __forceinline__ unsigned bitonic_sort64(unsigned key, int lane) {
#pragma unroll
    for (int k = 2; k <= 64; k <<= 1) {
#pragma unroll
        for (int j = k >> 1; j > 0; j >>= 1) {
            unsigned o = __shfl_xor(key, j);
            bool up       = ((lane & k) == 0);
            bool lower    = ((lane & j) == 0);
            bool takeMin  = (lower == up);
            bool mineLess = key < o;
            if (takeMin != mineLess) key = o;
        }
    }
    return key;
}
// Sort a bitonic 64-sequence ascending (cleanup half of a bitonic merge).
__device__ __forceinline__ unsigned bitonic_clean64(unsigned v, int lane) {
#pragma unroll
    for (int j = 32; j > 0; j >>= 1) {
        unsigned o = __shfl_xor(v, j);
        bool lower = ((lane & j) == 0);
        v = lower ? min(v, o) : max(v, o);
    }
    return v;
}
// Merge unsorted batch (1 key/lane) into sorted run, keep smallest 64 (verified R4).
__device__ __forceinline__ void merge_batch(unsigned& run, unsigned bk, int lane) {
    bk = bitonic_sort64(bk, lane);
    unsigned rev = __shfl(bk, 63 - lane);
    unsigned lo  = min(run, rev);
    run = bitonic_clean64(lo, lane);
}

__global__ __launch_bounds__(256)
void wfm_kernel(const float* __restrict__ x, const float* __restrict__ w1,
                const float* __restrict__ w2, float* __restrict__ out) {
    const int tid  = threadIdx.x;
    const int lane = tid & 63;
    const int wave = tid >> 6;
    const int pair = wave >> 1;      // which row-pair of the block
    const int half = wave & 1;       // which candidate half this wave scans
    const int b    = blockIdx.x >> 10;          // NPTS/4 = 1024 row-blocks
    const int rblk = blockIdx.x & 1023;
    const int n0   = rblk * 4;                  // 4 rows per block

    const float*  xb  = x + (size_t)b * NPTS * DF;
    const float4* xb4 = (const float4*)xb;

    __shared__ unsigned fifo[4][2][FIFO_N];     // per-wave per-row pending rings
    __shared__ unsigned mb[2][2][64];           // odd-wave published runs
    __shared__ float    w1n[CC][KNN];
    __shared__ float    w2n[CC][CO];
    __shared__ float    nrm[CC + CO];

    // ---- normalize weights (w1 rows over K, w2 cols over C) ----
    if (tid < CC) {
        float s = 0.f;
        for (int k = 0; k < KNN; ++k) { float v = w1[tid * KNN + k]; s = fmaf(v, v, s); }
        nrm[tid] = sqrtf(s);
    } else if (tid < CC + CO) {
        int o = tid - CC; float s = 0.f;
        for (int c = 0; c < CC; ++c) { float v = w2[c * CO + o]; s = fmaf(v, v, s); }
        nrm[tid] = sqrtf(s);
    }
    __syncthreads();
    if (tid < CC * KNN) w1n[tid >> 4][tid & 15] = w1[tid] / nrm[tid >> 4];
    if (tid < CC * CO)  w2n[tid >> 4][tid & 15] = w2[tid] / nrm[CC + (tid & 15)];
    // (visibility to epilogue covered by the single merge barrier below)

    // ---- this wave's 2 rows, features in registers ----
    const int r0 = n0 + pair * 2;
    float rf[2][DF];
#pragma unroll
    for (int r = 0; r < 2; ++r)
#pragma unroll
        for (int f = 0; f < DF; ++f)
            rf[r][f] = xb[(size_t)(r0 + r) * DF + f];

    // ---- barrier-free scan of this wave's candidate half ----
    unsigned run0 = 0xFFFFFFFFu, run1 = 0xFFFFFFFFu;
    unsigned T0 = 0xFFFFFFFFu,   T1 = 0xFFFFFFFFu;
    int base0 = 0, cnt0 = 0, base1 = 0, cnt1 = 0;
    unsigned* ff0 = &fifo[wave][0][0];
    unsigned* ff1 = &fifo[wave][1][0];

    auto accept = [&](unsigned key, unsigned& run, unsigned& T,
                      int& base, int& cnt, unsigned* ff) {
        bool acc = key < T;
        unsigned long long bal = __ballot(acc);
        if (bal) {                               // wave-uniform
            int pos = cnt + (int)__popcll(bal & ((1ull << lane) - 1ull));
            if (acc) ff[(base + pos) & (FIFO_N - 1)] = key;
            cnt += (int)__popcll(bal);
            __builtin_amdgcn_wave_barrier();
            asm volatile("" ::: "memory");
            while (cnt >= 64) {                  // wave-uniform
                unsigned bk = ff[(base + lane) & (FIFO_N - 1)];
                base += 64; cnt -= 64;
                merge_batch(run, bk, lane);
                T = __shfl(run, 63);
            }
        }
    };

    const int c0 = half * HALF;
#pragma unroll 1
    for (int t = 0; t < HALF; t += 64) {
        const int g = c0 + t + lane;                  // global candidate idx
        const float4* cp = xb4 + (size_t)g * 8;
        float sq = 0.f, dot0 = 0.f, dot1 = 0.f;
#pragma unroll
        for (int f4 = 0; f4 < 8; ++f4) {
            float4 v = cp[f4];                        // L1/L2-resident gather
            sq   = fmaf(v.x, v.x, sq);
            sq   = fmaf(v.y, v.y, sq);
            sq   = fmaf(v.z, v.z, sq);
            sq   = fmaf(v.w, v.w, sq);
            dot0 = fmaf(v.x, rf[0][f4*4+0], dot0);
            dot0 = fmaf(v.y, rf[0][f4*4+1], dot0);
            dot0 = fmaf(v.z, rf[0][f4*4+2], dot0);
            dot0 = fmaf(v.w, rf[0][f4*4+3], dot0);
            dot1 = fmaf(v.x, rf[1][f4*4+0], dot1);
            dot1 = fmaf(v.y, rf[1][f4*4+1], dot1);
            dot1 = fmaf(v.z, rf[1][f4*4+2], dot1);
            dot1 = fmaf(v.w, rf[1][f4*4+3], dot1);
        }
        float d0 = fmaf(-2.f, dot0, sq);   // sq_n const per row: order-free
        float d1 = fmaf(-2.f, dot1, sq);
        unsigned m = (unsigned)g;
        unsigned key0 = (sortable32(d0) & 0xFFFFF000u) | m;
        unsigned key1 = (sortable32(d1) & 0xFFFFF000u) | m;
        accept(key0, run0, T0, base0, cnt0, ff0);
        accept(key1, run1, T1, base1, cnt1, ff1);
    }

    // ---- drain pending (pad with +inf) ----
    if (cnt0 > 0) {
        unsigned bk = (lane < cnt0) ? ff0[(base0 + lane) & (FIFO_N - 1)] : 0xFFFFFFFFu;
        merge_batch(run0, bk, lane);
    }
    if (cnt1 > 0) {
        unsigned bk = (lane < cnt1) ? ff1[(base1 + lane) & (FIFO_N - 1)] : 0xFFFFFFFFu;
        merge_batch(run1, bk, lane);
    }

    // ---- single barrier: odd waves publish, even waves merge halves ----
    if (half == 1) { mb[pair][0][lane] = run0; mb[pair][1][lane] = run1; }
    __syncthreads();
    if (half == 1) return;
    // sorted+sorted merge keep-64: min with reversed other, then clean
    run0 = bitonic_clean64(min(run0, mb[pair][0][63 - lane]), lane);
    run1 = bitonic_clean64(min(run1, mb[pair][1][63 - lane]), lane);

    // ---- per row: canonical-fp32 re-rank of 64 survivors + output ----
    // dist32 = fl32( fl32(sq32[n] + sq32[m]) - fl32(2 * dot32) ), components
    // correctly rounded via fp64 accumulation. Ties break by LOWER index.
#pragma unroll
    for (int rr = 0; rr < 2; ++rr) {
        unsigned runv = (rr == 0) ? run0 : run1;
        int mym = (int)(runv & 0xFFFu);

        double dot64 = 0.0, sqm64 = 0.0, sqn64 = 0.0;
        const float* cp = xb + (size_t)mym * DF;
#pragma unroll
        for (int f = 0; f < DF; ++f) {
            double cv = (double)cp[f];
            double rv = (double)rf[rr][f];
            dot64 = fma(rv, cv, dot64);
            sqm64 = fma(cv, cv, sqm64);
            sqn64 = fma(rv, rv, sqn64);
        }
        float sqn32  = (float)sqn64;
        float sqm32  = (float)sqm64;
        float dot32  = (float)dot64;
        float dist32 = (sqn32 + sqm32) - 2.0f * dot32;

        unsigned long long key =
            ((unsigned long long)sortable32(dist32) << 32) | (unsigned)mym;

        // full-wave bitonic sort, ascending on (dist32, index) — verified R3/R4
#pragma unroll
        for (int k = 2; k <= 64; k <<= 1) {
#pragma unroll
            for (int j = k >> 1; j > 0; j >>= 1) {
                unsigned long long ok = __shfl_xor(key, j);
                bool up       = ((lane & k) == 0);
                bool lower    = ((lane & j) == 0);
                bool takeMin  = (lower == up);
                bool mineLess = (key < ok);
                if (takeMin != mineLess) key = ok;
            }
        }
        mym = (int)(key & 0xFFFFFFFFull);
        // lane k (k<16) now holds the rank-k neighbor index

        const int nn = r0 + rr;
        float wsum = 0.f;
#pragma unroll
        for (int k = 0; k < KNN; ++k) {
            int mk = __shfl(mym, k);                       // uniform
            float v = 0.f;
            if (lane < DF) v = xb[(size_t)mk * DF + lane]; // coalesced gather
            wsum = fmaf(v, w1n[lane & 7][k], wsum);        // lane = d*8+c
        }
        float ov = 0.f;
        const int d_ = lane >> 4, o_ = lane & 15;
#pragma unroll
        for (int c = 0; c < CC; ++c) {
            float wv = __shfl(wsum, d_ * CC + c);
            ov = fmaf(wv, w2n[c][o_], ov);
        }
        out[(size_t)(b * NPTS + nn) * (DD * CO) + lane] = ov;
    }
}

extern "C" void kernel_launch(void* const* d_in, const int* in_sizes, int n_in,
                              void* d_out, int out_size, void* d_ws, size_t ws_size,
                              hipStream_t stream) {
    const float* x  = (const float*)d_in[0];
    const float* w1 = (const float*)d_in[1];
    const float* w2 = (const float*)d_in[2];
    float* out = (float*)d_out;

    wfm_kernel<<<NB * (NPTS / 4), 256, 0, stream>>>(x, w1, w2, out);
}

// Round 6
// 365.271 us; speedup vs baseline: 1.4482x; 1.4482x over previous
//
#include <hip/hip_runtime.h>

#define NB    4
#define NPTS  4096
#define DF    32      // D*C
#define CC    8
#define CO    16
#define KNN   16
#define TILE  128     // candidates per LDS tile
#define FIFO_N 128    // per-row pending ring (max pending 63+64=127)

__device__ __forceinline__ unsigned sortable32(float f) {
    unsigned u = __float_as_uint(f);
    return (u & 0x80000000u) ? ~u : (u | 0x80000000u);
}

// Full-wave ascending bitonic sort of one u32 per lane (verified R3/R4).
__device__ __forceinline__ unsigned bitonic_sort64(unsigned key, int lane) {
#pragma unroll
    for (int k = 2; k <= 64; k <<= 1) {
#pragma unroll
        for (int j = k >> 1; j > 0; j >>= 1) {
            unsigned o = __shfl_xor(key, j);
            bool up       = ((lane & k) == 0);
            bool lower    = ((lane & j) == 0);
            bool takeMin  = (lower == up);
            bool mineLess = key < o;
            if (takeMin != mineLess) key = o;
        }
    }
    return key;
}
// Sort a bitonic 64-sequence ascending (cleanup half of bitonic merge).
__device__ __forceinline__ unsigned bitonic_clean64(unsigned v, int lane) {
#pragma unroll
    for (int j = 32; j > 0; j >>= 1) {
        unsigned o = __shfl_xor(v, j);
        bool lower = ((lane & j) == 0);
        v = lower ? min(v, o) : max(v, o);
    }
    return v;
}
// Merge unsorted batch into sorted run, keep smallest 64 (verified R4).
__device__ __forceinline__ void merge_batch(unsigned& run, unsigned bk, int lane) {
    bk = bitonic_sort64(bk, lane);
    unsigned rev = __shfl(bk, 63 - lane);
    unsigned lo  = min(run, rev);
    run = bitonic_clean64(lo, lane);
}

// per-point squared norm (fp32) -> d_ws
__global__ void sq_kernel(const float* __restrict__ x, float* __restrict__ sq) {
    int i = blockIdx.x * 256 + threadIdx.x;          // 0 .. NB*NPTS-1
    const float4* p = (const float4*)(x + (size_t)i * DF);
    float a = 0.f, b2 = 0.f;
#pragma unroll
    for (int f = 0; f < 8; ++f) {
        float4 v = p[f];
        a  = fmaf(v.x, v.x, a);  b2 = fmaf(v.y, v.y, b2);
        a  = fmaf(v.z, v.z, a);  b2 = fmaf(v.w, v.w, b2);
    }
    sq[i] = a + b2;
}

template <bool USE_SQG>
__global__ __launch_bounds__(256, 4)
void wfm_kernel(const float* __restrict__ x, const float* __restrict__ w1,
                const float* __restrict__ w2, const float* __restrict__ sqg,
                float* __restrict__ out) {
    const int tid  = threadIdx.x;
    const int lane = tid & 63;
    const int wave = tid >> 6;
    const int b    = blockIdx.x >> 9;           // 512 row-blocks per batch
    const int rblk = blockIdx.x & 511;
    const int n0   = rblk * 8 + wave * 2;       // 8 rows/block, 2 rows/wave

    const float*  xb  = x + (size_t)b * NPTS * DF;
    const float4* xb4 = (const float4*)xb;
    const float*  sqb = USE_SQG ? (sqg + b * NPTS) : nullptr;

    __shared__ float4   tileT[2][8 * TILE];     // double-buffered swizzled tile
    __shared__ unsigned fifo[4][2][FIFO_N];     // per-wave per-row pending rings
    __shared__ float    w1n[CC][KNN];
    __shared__ float    w2n[CC][CO];
    __shared__ float    nrm[CC + CO];

    // ---- normalize weights (w1 rows over K, w2 cols over C) ----
    if (tid < CC) {
        float s = 0.f;
        for (int k = 0; k < KNN; ++k) { float v = w1[tid * KNN + k]; s = fmaf(v, v, s); }
        nrm[tid] = sqrtf(s);
    } else if (tid < CC + CO) {
        int o = tid - CC; float s = 0.f;
        for (int c = 0; c < CC; ++c) { float v = w2[c * CO + o]; s = fmaf(v, v, s); }
        nrm[tid] = sqrtf(s);
    }
    __syncthreads();
    if (tid < CC * KNN) w1n[tid >> 4][tid & 15] = w1[tid] / nrm[tid >> 4];
    if (tid < CC * CO)  w2n[tid >> 4][tid & 15] = w2[tid] / nrm[CC + (tid & 15)];
    // visibility to epilogue covered by the scan's per-tile barriers

    // ---- row features (2 rows per wave, in registers) ----
    float rf[2][DF];
#pragma unroll
    for (int r = 0; r < 2; ++r)
#pragma unroll
        for (int f = 0; f < DF; ++f)
            rf[r][f] = xb[(size_t)(n0 + r) * DF + f];

    // ---- scan state ----
    unsigned run0 = 0xFFFFFFFFu, run1 = 0xFFFFFFFFu;
    unsigned T0 = 0xFFFFFFFFu,   T1 = 0xFFFFFFFFu;
    int base0 = 0, cnt0 = 0, base1 = 0, cnt1 = 0;
    unsigned* ff0 = &fifo[wave][0][0];
    unsigned* ff1 = &fifo[wave][1][0];

    auto accept = [&](unsigned key, unsigned& run, unsigned& T,
                      int& base, int& cnt, unsigned* ff) {
        bool acc = key < T;
        unsigned long long bal = __ballot(acc);
        if (bal) {                               // wave-uniform
            int pos = cnt + (int)__popcll(bal & ((1ull << lane) - 1ull));
            if (acc) ff[(base + pos) & (FIFO_N - 1)] = key;
            cnt += (int)__popcll(bal);
            __builtin_amdgcn_wave_barrier();
            asm volatile("" ::: "memory");
            if (cnt >= 64) {                     // at most one merge per call
                unsigned bk = ff[(base + lane) & (FIFO_N - 1)];
                base += 64; cnt -= 64;
                merge_batch(run, bk, lane);
                T = __shfl(run, 63);
            }
        }
    };

    // ---- tiled scan: double-buffered LDS, ONE barrier per tile ----
    float4 pf[4];
#pragma unroll
    for (int q = 0; q < 4; ++q) pf[q] = xb4[q * 256 + tid];   // tile 0

    int cur = 0;
#pragma unroll 1
    for (int t = 0; t < NPTS; t += TILE) {
#pragma unroll
        for (int q = 0; q < 4; ++q) {            // write tile t into buf[cur]
            int idx = q * 256 + tid;
            int cand = idx >> 3, f4 = idx & 7;
            tileT[cur][f4 * TILE + (cand ^ f4)] = pf[q];
        }
        __syncthreads();                         // buf[cur] ready (and reusable)
        int tn = (t + TILE < NPTS) ? (t + TILE) : 0;
#pragma unroll
        for (int q = 0; q < 4; ++q)              // prefetch next tile (hidden)
            pf[q] = xb4[(size_t)tn * 8 + q * 256 + tid];

        unsigned k0[2], k1[2];
#pragma unroll
        for (int p = 0; p < 2; ++p) {            // pure key computation, no LDS-fence
            const int c = p * 64 + lane;
            float d0a = 0.f, d0b = 0.f, d1a = 0.f, d1b = 0.f;
            float sa = 0.f, sb = 0.f;
#pragma unroll
            for (int f4 = 0; f4 < 8; ++f4) {
                float4 v = tileT[cur][f4 * TILE + (c ^ f4)];   // conflict-free b128
                if constexpr (!USE_SQG) {
                    sa = fmaf(v.x, v.x, sa); sb = fmaf(v.y, v.y, sb);
                    sa = fmaf(v.z, v.z, sa); sb = fmaf(v.w, v.w, sb);
                }
                d0a = fmaf(v.x, rf[0][f4*4+0], d0a);
                d0b = fmaf(v.y, rf[0][f4*4+1], d0b);
                d0a = fmaf(v.z, rf[0][f4*4+2], d0a);
                d0b = fmaf(v.w, rf[0][f4*4+3], d0b);
                d1a = fmaf(v.x, rf[1][f4*4+0], d1a);
                d1b = fmaf(v.y, rf[1][f4*4+1], d1b);
                d1a = fmaf(v.z, rf[1][f4*4+2], d1a);
                d1b = fmaf(v.w, rf[1][f4*4+3], d1b);
            }
            float sqv = USE_SQG ? sqb[t + c] : (sa + sb);
            float d0 = fmaf(-2.f, d0a + d0b, sqv);   // sq_n const/row: order-free
            float d1 = fmaf(-2.f, d1a + d1b, sqv);
            unsigned m = (unsigned)(t + c);
            k0[p] = (sortable32(d0) & 0xFFFFF000u) | m;
            k1[p] = (sortable32(d1) & 0xFFFFF000u) | m;
        }
        accept(k0[0], run0, T0, base0, cnt0, ff0);
        accept(k0[1], run0, T0, base0, cnt0, ff0);
        accept(k1[0], run1, T1, base1, cnt1, ff1);
        accept(k1[1], run1, T1, base1, cnt1, ff1);
        cur ^= 1;
    }

    // ---- drain pending (pad with +inf) ----
    if (cnt0 > 0) {
        unsigned bk = (lane < cnt0) ? ff0[(base0 + lane) & (FIFO_N - 1)] : 0xFFFFFFFFu;
        merge_batch(run0, bk, lane);
    }
    if (cnt1 > 0) {
        unsigned bk = (lane < cnt1) ? ff1[(base1 + lane) & (FIFO_N - 1)] : 0xFFFFFFFFu;
        merge_batch(run1, bk, lane);
    }

    // ---- per row: canonical-fp32 re-rank of 64 survivors + output ----
    // dist32 = fl32( fl32(sq32[n] + sq32[m]) - fl32(2 * dot32) ), components
    // correctly rounded via fp64 accumulation. Ties break by LOWER index.
#pragma unroll
    for (int rr = 0; rr < 2; ++rr) {
        unsigned runv = (rr == 0) ? run0 : run1;
        int mym = (int)(runv & 0xFFFu);

        double dot64 = 0.0, sqm64 = 0.0, sqn64 = 0.0;
        const float* cp = xb + (size_t)mym * DF;
#pragma unroll
        for (int f = 0; f < DF; ++f) {
            double cv = (double)cp[f];
            double rv = (double)rf[rr][f];
            dot64 = fma(rv, cv, dot64);
            sqm64 = fma(cv, cv, sqm64);
            sqn64 = fma(rv, rv, sqn64);
        }
        float sqn32  = (float)sqn64;
        float sqm32  = (float)sqm64;
        float dot32  = (float)dot64;
        float dist32 = (sqn32 + sqm32) - 2.0f * dot32;

        unsigned long long key =
            ((unsigned long long)sortable32(dist32) << 32) | (unsigned)mym;

        // full-wave bitonic sort, ascending on (dist32, index) — verified R3/R4
#pragma unroll
        for (int k = 2; k <= 64; k <<= 1) {
#pragma unroll
            for (int j = k >> 1; j > 0; j >>= 1) {
                unsigned long long ok = __shfl_xor(key, j);
                bool up       = ((lane & k) == 0);
                bool lower    = ((lane & j) == 0);
                bool takeMin  = (lower == up);
                bool mineLess = (key < ok);
                if (takeMin != mineLess) key = ok;
            }
        }
        mym = (int)(key & 0xFFFFFFFFull);
        // lane k (k<16) now holds the rank-k neighbor index

        const int nn = n0 + rr;
        float wsum = 0.f;
#pragma unroll
        for (int k = 0; k < KNN; ++k) {
            int mk = __shfl(mym, k);                       // uniform
            float v = 0.f;
            if (lane < DF) v = xb[(size_t)mk * DF + lane]; // coalesced gather
            wsum = fmaf(v, w1n[lane & 7][k], wsum);        // lane = d*8+c
        }
        float ov = 0.f;
        const int d_ = lane >> 4, o_ = lane & 15;
#pragma unroll
        for (int c = 0; c < CC; ++c) {
            float wv = __shfl(wsum, d_ * CC + c);
            ov = fmaf(wv, w2n[c][o_], ov);
        }
        out[(size_t)(b * NPTS + nn) * (4 * CO) + lane] = ov;
    }
}

extern "C" void kernel_launch(void* const* d_in, const int* in_sizes, int n_in,
                              void* d_out, int out_size, void* d_ws, size_t ws_size,
                              hipStream_t stream) {
    const float* x  = (const float*)d_in[0];
    const float* w1 = (const float*)d_in[1];
    const float* w2 = (const float*)d_in[2];
    float* out = (float*)d_out;

    if (ws_size >= (size_t)NB * NPTS * sizeof(float)) {
        float* sq = (float*)d_ws;
        sq_kernel<<<NB * NPTS / 256, 256, 0, stream>>>(x, sq);
        wfm_kernel<true><<<NB * (NPTS / 8), 256, 0, stream>>>(x, w1, w2, sq, out);
    } else {
        wfm_kernel<false><<<NB * (NPTS / 8), 256, 0, stream>>>(x, w1, w2, nullptr, out);
    }
}

// Round 7
// 214.488 us; speedup vs baseline: 2.4662x; 1.7030x over previous
//
#include <hip/hip_runtime.h>
#include <hip/hip_fp16.h>

#define NB    4
#define NPTS  4096
#define DF    32      // D*C
#define CC    8
#define CO    16
#define KNN   16
#define TILE16 256    // candidates per LDS tile (f16 path)
#define TILE32 128    // candidates per LDS tile (fp32 fallback)
#define FIFO_N 128    // per-row pending ring (max pending 63+64=127)

__device__ __forceinline__ unsigned sortable32(float f) {
    unsigned u = __float_as_uint(f);
    return (u & 0x80000000u) ? ~u : (u | 0x80000000u);
}

// Full-wave ascending bitonic sort of one u32 per lane (verified R3/R4).
__device__ __forceinline__ unsigned bitonic_sort64(unsigned key, int lane) {
#pragma unroll
    for (int k = 2; k <= 64; k <<= 1) {
#pragma unroll
        for (int j = k >> 1; j > 0; j >>= 1) {
            unsigned o = __shfl_xor(key, j);
            bool up       = ((lane & k) == 0);
            bool lower    = ((lane & j) == 0);
            bool takeMin  = (lower == up);
            bool mineLess = key < o;
            if (takeMin != mineLess) key = o;
        }
    }
    return key;
}
__device__ __forceinline__ unsigned bitonic_clean64(unsigned v, int lane) {
#pragma unroll
    for (int j = 32; j > 0; j >>= 1) {
        unsigned o = __shfl_xor(v, j);
        bool lower = ((lane & j) == 0);
        v = lower ? min(v, o) : max(v, o);
    }
    return v;
}
__device__ __forceinline__ void merge_batch(unsigned& run, unsigned bk, int lane) {
    bk = bitonic_sort64(bk, lane);
    unsigned rev = __shfl(bk, 63 - lane);
    unsigned lo  = min(run, rev);
    run = bitonic_clean64(lo, lane);
}

// ---- prep: per-point squared norm (fp32) + half2-packed copy of x ----
__global__ void prep_kernel(const float* __restrict__ x, float* __restrict__ sq,
                            __half2* __restrict__ xh) {
    int i = blockIdx.x * 256 + threadIdx.x;          // 0 .. NB*NPTS-1
    const float4* p = (const float4*)(x + (size_t)i * DF);
    __half2* ho = xh + (size_t)i * 16;
    float a = 0.f, b2 = 0.f;
#pragma unroll
    for (int f = 0; f < 8; ++f) {
        float4 v = p[f];
        a  = fmaf(v.x, v.x, a);  b2 = fmaf(v.y, v.y, b2);
        a  = fmaf(v.z, v.z, a);  b2 = fmaf(v.w, v.w, b2);
        ho[f * 2 + 0] = __floats2half2_rn(v.x, v.y);
        ho[f * 2 + 1] = __floats2half2_rn(v.z, v.w);
    }
    sq[i] = a + b2;
}

// ================= shared epilogue: canonical-fp32 re-rank + output ========
// (verified R3-R6 verbatim logic; fp32 row features re-read from global here)
__device__ __forceinline__ void rerank_and_emit(
    unsigned runv, int nn, const float* __restrict__ xb,
    const float (*w1n)[KNN], const float (*w2n)[CO],
    float* __restrict__ out, int bb, int lane) {

    int mym = (int)(runv & 0xFFFu);
    const float* rp = xb + (size_t)nn * DF;
    const float* cp = xb + (size_t)mym * DF;
    double dot64 = 0.0, sqm64 = 0.0, sqn64 = 0.0;
#pragma unroll
    for (int f = 0; f < DF; ++f) {
        double cv = (double)cp[f];
        double rv = (double)rp[f];
        dot64 = fma(rv, cv, dot64);
        sqm64 = fma(cv, cv, sqm64);
        sqn64 = fma(rv, rv, sqn64);
    }
    float dist32 = ((float)sqn64 + (float)sqm64) - 2.0f * (float)dot64;

    unsigned long long key =
        ((unsigned long long)sortable32(dist32) << 32) | (unsigned)mym;
#pragma unroll
    for (int k = 2; k <= 64; k <<= 1) {
#pragma unroll
        for (int j = k >> 1; j > 0; j >>= 1) {
            unsigned long long ok = __shfl_xor(key, j);
            bool up       = ((lane & k) == 0);
            bool lower    = ((lane & j) == 0);
            bool takeMin  = (lower == up);
            bool mineLess = (key < ok);
            if (takeMin != mineLess) key = ok;
        }
    }
    mym = (int)(key & 0xFFFFFFFFull);

    float wsum = 0.f;
#pragma unroll
    for (int k = 0; k < KNN; ++k) {
        int mk = __shfl(mym, k);                       // uniform
        float v = 0.f;
        if (lane < DF) v = xb[(size_t)mk * DF + lane]; // coalesced gather
        wsum = fmaf(v, w1n[lane & 7][k], wsum);        // lane = d*8+c
    }
    float ov = 0.f;
    const int d_ = lane >> 4, o_ = lane & 15;
#pragma unroll
    for (int c = 0; c < CC; ++c) {
        float wv = __shfl(wsum, d_ * CC + c);
        ov = fmaf(wv, w2n[c][o_], ov);
    }
    out[(size_t)(bb * NPTS + nn) * (4 * CO) + lane] = ov;
}

// ======================= f16-scan kernel (primary) =========================
__global__ __launch_bounds__(256, 3)
void wfm16_kernel(const float* __restrict__ x, const __half2* __restrict__ xh,
                  const float* __restrict__ sqg, const float* __restrict__ w1,
                  const float* __restrict__ w2, float* __restrict__ out) {
    const int tid  = threadIdx.x;
    const int lane = tid & 63;
    const int wave = tid >> 6;
    const int b    = blockIdx.x >> 9;           // 512 row-blocks per batch
    const int rblk = blockIdx.x & 511;
    const int n0   = rblk * 8 + wave * 2;       // 8 rows/block, 2 rows/wave

    const float* xb  = x + (size_t)b * NPTS * DF;
    const uint4* xhs = (const uint4*)(xh + (size_t)b * NPTS * 16); // 16B slots
    const float* sqb = sqg + b * NPTS;

    __shared__ uint4    tile[2][TILE16 * 4];    // 16B slots, XOR-swizzled
    __shared__ unsigned fifo[4][2][FIFO_N];
    __shared__ float    w1n[CC][KNN];
    __shared__ float    w2n[CC][CO];
    __shared__ float    nrm[CC + CO];

    // ---- normalize weights ----
    if (tid < CC) {
        float s = 0.f;
        for (int k = 0; k < KNN; ++k) { float v = w1[tid * KNN + k]; s = fmaf(v, v, s); }
        nrm[tid] = sqrtf(s);
    } else if (tid < CC + CO) {
        int o = tid - CC; float s = 0.f;
        for (int c = 0; c < CC; ++c) { float v = w2[c * CO + o]; s = fmaf(v, v, s); }
        nrm[tid] = sqrtf(s);
    }
    __syncthreads();
    if (tid < CC * KNN) w1n[tid >> 4][tid & 15] = w1[tid] / nrm[tid >> 4];
    if (tid < CC * CO)  w2n[tid >> 4][tid & 15] = w2[tid] / nrm[CC + (tid & 15)];
    // visibility to epilogue covered by the scan's per-tile barriers

    // ---- row features, packed half2 (32 VGPRs) ----
    __half2 rf2[2][16];
    {
        const __half2* hb = xh + (size_t)b * NPTS * 16;
#pragma unroll
        for (int r = 0; r < 2; ++r)
#pragma unroll
            for (int j = 0; j < 16; ++j)
                rf2[r][j] = hb[(size_t)(n0 + r) * 16 + j];
    }

    // ---- scan state ----
    unsigned run0 = 0xFFFFFFFFu, run1 = 0xFFFFFFFFu;
    unsigned T0 = 0xFFFFFFFFu,   T1 = 0xFFFFFFFFu;
    int base0 = 0, cnt0 = 0, base1 = 0, cnt1 = 0;
    unsigned* ff0 = &fifo[wave][0][0];
    unsigned* ff1 = &fifo[wave][1][0];

    auto accept = [&](unsigned key, unsigned& run, unsigned& T,
                      int& base, int& cnt, unsigned* ff) {
        bool acc = key < T;
        unsigned long long bal = __ballot(acc);
        if (bal) {                               // wave-uniform
            int pos = cnt + (int)__popcll(bal & ((1ull << lane) - 1ull));
            if (acc) ff[(base + pos) & (FIFO_N - 1)] = key;
            cnt += (int)__popcll(bal);
            __builtin_amdgcn_wave_barrier();
            asm volatile("" ::: "memory");
            if (cnt >= 64) {
                unsigned bk = ff[(base + lane) & (FIFO_N - 1)];
                base += 64; cnt -= 64;
                merge_batch(run, bk, lane);
                T = __shfl(run, 63);
            }
        }
    };

    // ---- tiled scan: double-buffered LDS, ONE barrier per tile ----
    int cur = 0;
#pragma unroll 1
    for (int t = 0; t < NPTS; t += TILE16) {
#pragma unroll
        for (int q = 0; q < 4; ++q) {            // stage tile t into buf[cur]
            int s = q * 256 + tid;               // lds 16B-slot 0..1023
            int c = s >> 2;                      // tile-local candidate
            int f = (s & 3) ^ ((c >> 1) & 3);    // inverse of read swizzle
            tile[cur][s] = xhs[(size_t)(t + c) * 4 + f];
        }
        __syncthreads();                         // buf[cur] ready

        unsigned k0[4], k1[4];
#pragma unroll
        for (int p = 0; p < 4; ++p) {            // pure key computation
            const int c = p * 64 + lane;
            const int w = (c >> 1) & 3;
            const uint4* tb = &tile[cur][c * 4];
            __half2 a0 = __float2half2_rn(0.f), b0 = a0, a1 = a0, b1 = a0;
#pragma unroll
            for (int f = 0; f < 4; ++f) {
                uint4 v = tb[f ^ w];             // conflict-free b128
                __half2 x0 = __builtin_bit_cast(__half2, v.x);
                __half2 x1 = __builtin_bit_cast(__half2, v.y);
                __half2 x2 = __builtin_bit_cast(__half2, v.z);
                __half2 x3 = __builtin_bit_cast(__half2, v.w);
                a0 = __hfma2(x0, rf2[0][f*4+0], a0);
                b0 = __hfma2(x1, rf2[0][f*4+1], b0);
                a0 = __hfma2(x2, rf2[0][f*4+2], a0);
                b0 = __hfma2(x3, rf2[0][f*4+3], b0);
                a1 = __hfma2(x0, rf2[1][f*4+0], a1);
                b1 = __hfma2(x1, rf2[1][f*4+1], b1);
                a1 = __hfma2(x2, rf2[1][f*4+2], a1);
                b1 = __hfma2(x3, rf2[1][f*4+3], b1);
            }
            float dot0 = (__low2float(a0) + __high2float(a0))
                       + (__low2float(b0) + __high2float(b0));
            float dot1 = (__low2float(a1) + __high2float(a1))
                       + (__low2float(b1) + __high2float(b1));
            float sqv = sqb[t + c];
            float d0 = fmaf(-2.f, dot0, sqv);    // sq_n const/row: order-free
            float d1 = fmaf(-2.f, dot1, sqv);
            unsigned m = (unsigned)(t + c);
            k0[p] = (sortable32(d0) & 0xFFFFF000u) | m;
            k1[p] = (sortable32(d1) & 0xFFFFF000u) | m;
        }
#pragma unroll
        for (int p = 0; p < 4; ++p) accept(k0[p], run0, T0, base0, cnt0, ff0);
#pragma unroll
        for (int p = 0; p < 4; ++p) accept(k1[p], run1, T1, base1, cnt1, ff1);
        cur ^= 1;
    }

    // ---- drain pending (pad with +inf) ----
    if (cnt0 > 0) {
        unsigned bk = (lane < cnt0) ? ff0[(base0 + lane) & (FIFO_N - 1)] : 0xFFFFFFFFu;
        merge_batch(run0, bk, lane);
    }
    if (cnt1 > 0) {
        unsigned bk = (lane < cnt1) ? ff1[(base1 + lane) & (FIFO_N - 1)] : 0xFFFFFFFFu;
        merge_batch(run1, bk, lane);
    }

    rerank_and_emit(run0, n0 + 0, xb, w1n, w2n, out, b, lane);
    rerank_and_emit(run1, n0 + 1, xb, w1n, w2n, out, b, lane);
}

// ================= fp32 fallback (R6 structure, proven) ====================
__global__ __launch_bounds__(256)
void wfm32_kernel(const float* __restrict__ x, const float* __restrict__ w1,
                  const float* __restrict__ w2, float* __restrict__ out) {
    const int tid  = threadIdx.x;
    const int lane = tid & 63;
    const int wave = tid >> 6;
    const int b    = blockIdx.x >> 9;
    const int rblk = blockIdx.x & 511;
    const int n0   = rblk * 8 + wave * 2;

    const float*  xb  = x + (size_t)b * NPTS * DF;
    const float4* xb4 = (const float4*)xb;

    __shared__ float4   tileT[2][8 * TILE32];
    __shared__ unsigned fifo[4][2][FIFO_N];
    __shared__ float    w1n[CC][KNN];
    __shared__ float    w2n[CC][CO];
    __shared__ float    nrm[CC + CO];

    if (tid < CC) {
        float s = 0.f;
        for (int k = 0; k < KNN; ++k) { float v = w1[tid * KNN + k]; s = fmaf(v, v, s); }
        nrm[tid] = sqrtf(s);
    } else if (tid < CC + CO) {
        int o = tid - CC; float s = 0.f;
        for (int c = 0; c < CC; ++c) { float v = w2[c * CO + o]; s = fmaf(v, v, s); }
        nrm[tid] = sqrtf(s);
    }
    __syncthreads();
    if (tid < CC * KNN) w1n[tid >> 4][tid & 15] = w1[tid] / nrm[tid >> 4];
    if (tid < CC * CO)  w2n[tid >> 4][tid & 15] = w2[tid] / nrm[CC + (tid & 15)];

    float rf[2][DF];
#pragma unroll
    for (int r = 0; r < 2; ++r)
#pragma unroll
        for (int f = 0; f < DF; ++f)
            rf[r][f] = xb[(size_t)(n0 + r) * DF + f];

    unsigned run0 = 0xFFFFFFFFu, run1 = 0xFFFFFFFFu;
    unsigned T0 = 0xFFFFFFFFu,   T1 = 0xFFFFFFFFu;
    int base0 = 0, cnt0 = 0, base1 = 0, cnt1 = 0;
    unsigned* ff0 = &fifo[wave][0][0];
    unsigned* ff1 = &fifo[wave][1][0];

    auto accept = [&](unsigned key, unsigned& run, unsigned& T,
                      int& base, int& cnt, unsigned* ff) {
        bool acc = key < T;
        unsigned long long bal = __ballot(acc);
        if (bal) {
            int pos = cnt + (int)__popcll(bal & ((1ull << lane) - 1ull));
            if (acc) ff[(base + pos) & (FIFO_N - 1)] = key;
            cnt += (int)__popcll(bal);
            __builtin_amdgcn_wave_barrier();
            asm volatile("" ::: "memory");
            if (cnt >= 64) {
                unsigned bk = ff[(base + lane) & (FIFO_N - 1)];
                base += 64; cnt -= 64;
                merge_batch(run, bk, lane);
                T = __shfl(run, 63);
            }
        }
    };

    float4 pf[4];
#pragma unroll
    for (int q = 0; q < 4; ++q) pf[q] = xb4[q * 256 + tid];

    int cur = 0;
#pragma unroll 1
    for (int t = 0; t < NPTS; t += TILE32) {
#pragma unroll
        for (int q = 0; q < 4; ++q) {
            int idx = q * 256 + tid;
            int cand = idx >> 3, f4 = idx & 7;
            tileT[cur][f4 * TILE32 + (cand ^ f4)] = pf[q];
        }
        __syncthreads();
        int tn = (t + TILE32 < NPTS) ? (t + TILE32) : 0;
#pragma unroll
        for (int q = 0; q < 4; ++q)
            pf[q] = xb4[(size_t)tn * 8 + q * 256 + tid];

        unsigned k0[2], k1[2];
#pragma unroll
        for (int p = 0; p < 2; ++p) {
            const int c = p * 64 + lane;
            float d0a = 0.f, d0b = 0.f, d1a = 0.f, d1b = 0.f;
            float sa = 0.f, sb = 0.f;
#pragma unroll
            for (int f4 = 0; f4 < 8; ++f4) {
                float4 v = tileT[cur][f4 * TILE32 + (c ^ f4)];
                sa = fmaf(v.x, v.x, sa); sb = fmaf(v.y, v.y, sb);
                sa = fmaf(v.z, v.z, sa); sb = fmaf(v.w, v.w, sb);
                d0a = fmaf(v.x, rf[0][f4*4+0], d0a);
                d0b = fmaf(v.y, rf[0][f4*4+1], d0b);
                d0a = fmaf(v.z, rf[0][f4*4+2], d0a);
                d0b = fmaf(v.w, rf[0][f4*4+3], d0b);
                d1a = fmaf(v.x, rf[1][f4*4+0], d1a);
                d1b = fmaf(v.y, rf[1][f4*4+1], d1b);
                d1a = fmaf(v.z, rf[1][f4*4+2], d1a);
                d1b = fmaf(v.w, rf[1][f4*4+3], d1b);
            }
            float sqv = sa + sb;
            float d0 = fmaf(-2.f, d0a + d0b, sqv);
            float d1 = fmaf(-2.f, d1a + d1b, sqv);
            unsigned m = (unsigned)(t + c);
            k0[p] = (sortable32(d0) & 0xFFFFF000u) | m;
            k1[p] = (sortable32(d1) & 0xFFFFF000u) | m;
        }
        accept(k0[0], run0, T0, base0, cnt0, ff0);
        accept(k0[1], run0, T0, base0, cnt0, ff0);
        accept(k1[0], run1, T1, base1, cnt1, ff1);
        accept(k1[1], run1, T1, base1, cnt1, ff1);
        cur ^= 1;
    }

    if (cnt0 > 0) {
        unsigned bk = (lane < cnt0) ? ff0[(base0 + lane) & (FIFO_N - 1)] : 0xFFFFFFFFu;
        merge_batch(run0, bk, lane);
    }
    if (cnt1 > 0) {
        unsigned bk = (lane < cnt1) ? ff1[(base1 + lane) & (FIFO_N - 1)] : 0xFFFFFFFFu;
        merge_batch(run1, bk, lane);
    }

    rerank_and_emit(run0, n0 + 0, xb, w1n, w2n, out, b, lane);
    rerank_and_emit(run1, n0 + 1, xb, w1n, w2n, out, b, lane);
}

extern "C" void kernel_launch(void* const* d_in, const int* in_sizes, int n_in,
                              void* d_out, int out_size, void* d_ws, size_t ws_size,
                              hipStream_t stream) {
    const float* x  = (const float*)d_in[0];
    const float* w1 = (const float*)d_in[1];
    const float* w2 = (const float*)d_in[2];
    float* out = (float*)d_out;

    const size_t sq_bytes = (size_t)NB * NPTS * sizeof(float);      // 64 KB
    const size_t xh_bytes = (size_t)NB * NPTS * DF * sizeof(__half); // 1 MB

    if (ws_size >= sq_bytes + xh_bytes) {
        float*   sq = (float*)d_ws;
        __half2* xh = (__half2*)((char*)d_ws + sq_bytes);
        prep_kernel<<<NB * NPTS / 256, 256, 0, stream>>>(x, sq, xh);
        wfm16_kernel<<<NB * (NPTS / 8), 256, 0, stream>>>(x, xh, sq, w1, w2, out);
    } else {
        wfm32_kernel<<<NB * (NPTS / 8), 256, 0, stream>>>(x, w1, w2, out);
    }
}